// Round 3
// baseline (58.395 us; speedup 1.0000x reference)
//
#include <hip/hip_runtime.h>

// ToKmerLayer: one-hot conv1d + threshold == exact 3-mer match indicator.
// out[b,p,f] = 1.0 iff window code (base-4, MSB first) == code(feature f).
//
// Store-stream form: each wave needs codes for 64 distinct positions per
// 256-position tile. One position per lane: 3 float4 loads ONCE in the
// prologue, code computed in-register, then the 16-iteration store loop is
// {1 broadcast ds_bpermute + 4 cmp + 4 sel + 1 NT dwordx4 store} -- the same
// shape as the 6.9 TB/s fillBuffer stream. No LDS allocation, no barriers.

typedef float f32x4 __attribute__((ext_vector_type(4)));

constexpr int B = 64;
constexpr int L = 16384;
constexpr int F = 64;
constexpr int P = L - 2;              // 16382 output positions per row (k=3)
constexpr int T = 256;                // positions per block tile
constexpr int BPR = (P + T - 1) / T;  // 64 tiles per row

struct CodeTab { int c[64]; };        // feature -> code

__global__ __launch_bounds__(256) void kmer_kernel(
    const float* __restrict__ in,     // (B, L, 4) one-hot
    float* __restrict__ out,          // (B, P, F)
    CodeTab tab)
{
    const int tid  = threadIdx.x;
    const int lane = tid & 63;
    const int w    = tid >> 6;        // wave id (0..3)
    const int b    = blockIdx.x / BPR;
    const int p0   = (blockIdx.x % BPR) * T;
    const int q    = lane & 15;       // this thread's 4-feature slice
    const int g    = lane >> 4;       // 16-lane group within wave

    // loop-invariant target codes for features 4q..4q+3
    const int c0 = tab.c[4 * q + 0];
    const int c1 = tab.c[4 * q + 1];
    const int c2 = tab.c[4 * q + 2];
    const int c3 = tab.c[4 * q + 3];

    // --- prologue: each lane owns one position, loads once, computes code ---
    // wave w stores chunks with lp = 4w + (lane>>4) + 16*it  -> owned set:
    const int lpOwn = 4 * w + (lane & 3) + 16 * (lane >> 2);
    int p = p0 + lpOwn;
    p = p < P ? p : P - 1;            // clamp (last tile only); p+2 <= L-1

    const f32x4* rowIn = reinterpret_cast<const f32x4*>(in) + (size_t)b * L;
    const f32x4 a0 = rowIn[p];
    const f32x4 a1 = rowIn[p + 1];
    const f32x4 a2 = rowIn[p + 2];
    const float d0 = fmaf(3.f, a0.w, fmaf(2.f, a0.z, a0.y));
    const float d1 = fmaf(3.f, a1.w, fmaf(2.f, a1.z, a1.y));
    const float d2 = fmaf(3.f, a2.w, fmaf(2.f, a2.z, a2.y));
    const int myCode = (int)fmaf(16.f, d0, fmaf(4.f, d1, d2));

    // --- store burst: code arrives via broadcast shuffle, no loads ---
    const int nPos = min(T, P - p0);  // 256, or 254 in the last tile per row
    f32x4* outBase =
        reinterpret_cast<f32x4*>(out) + ((size_t)b * P + p0) * (F / 4);

    if (nPos == T) {                  // hot path: 4032 of 4096 blocks
        #pragma unroll
        for (int it = 0; it < 16; ++it) {
            const int code = __shfl(myCode, (it << 2) | g, 64);
            f32x4 v;
            v.x = (code == c0) ? 1.f : 0.f;
            v.y = (code == c1) ? 1.f : 0.f;
            v.z = (code == c2) ? 1.f : 0.f;
            v.w = (code == c3) ? 1.f : 0.f;
            __builtin_nontemporal_store(v, outBase + tid + 256 * it);
        }
    } else {                          // tail tile: mask dead positions
        #pragma unroll
        for (int it = 0; it < 16; ++it) {
            const int i = tid + 256 * it;
            const int code = __shfl(myCode, (it << 2) | g, 64);
            f32x4 v;
            v.x = (code == c0) ? 1.f : 0.f;
            v.y = (code == c1) ? 1.f : 0.f;
            v.z = (code == c2) ? 1.f : 0.f;
            v.w = (code == c3) ? 1.f : 0.f;
            if ((i >> 4) < nPos)
                __builtin_nontemporal_store(v, outBase + i);
        }
    }
}

extern "C" void kernel_launch(void* const* d_in, const int* in_sizes, int n_in,
                              void* d_out, int out_size, void* d_ws, size_t ws_size,
                              hipStream_t stream) {
    const float* in = (const float*)d_in[0];
    // d_in[1] (one-hot kernel) and d_in[2] (k) are fixed by the reference's
    // deterministic build_kernel(3); the permutation is replicated here.
    float* out = (float*)d_out;

    // Replicate ToKmerLayer.build_kernel's deque ordering for k=3:
    // pair t (ascending-i order): appendleft(rc) -> index 31-t; append(i) -> 32+t.
    CodeTab tab;
    {
        bool seen[64] = {};
        int t = 0;
        for (int i = 0; i < 64; ++i) {
            const int d0 = (i >> 4) & 3, d1 = (i >> 2) & 3, d2 = i & 3;
            const int rc = ((3 - d2) << 4) | ((3 - d1) << 2) | (3 - d0);
            if (!seen[rc]) {
                seen[rc] = true;
                seen[i]  = true;
                tab.c[31 - t] = rc;   // reverse-complement kernel, appendleft
                tab.c[32 + t] = i;    // forward kernel, append
                ++t;
            }
        }
    }

    dim3 grid(B * BPR);  // 4096 blocks
    kmer_kernel<<<grid, 256, 0, stream>>>(in, out, tab);
}